// Round 5
// baseline (208.670 us; speedup 1.0000x reference)
//
#include <hip/hip_runtime.h>

// AtomDistances: out[b,i,j] = mask[b,i]&&mask[b,j]&&(i!=j)
//                  ? 1/(safe_norm(pos[b,nbr[b,i,j]] - pos[b,i]) + 1e-8) : 0
// B=4, A=2048.
//
// R5: R3 structure + work-stealing row tickets (per-batch atomic counter in
// d_ws, zeroed by a tiny hipMemsetAsync graph node). Waves claim rows
// dynamically -> active rows spread evenly over CUs (fixes Binomial(32,1/2)
// per-CU makespan tail) with no prepass kernel. Ticket claim is prefetched
// one row ahead. Depth-4 neighbor prefetch, nt stores, rsqrt kept from R3;
// LDS packed as x(b32) + yz(b64).

typedef float f4 __attribute__((ext_vector_type(4)));
typedef float f2 __attribute__((ext_vector_type(2)));

constexpr int A_DIM = 2048;
constexpr int WPB   = 8;          // waves per block
constexpr int NTHR  = WPB * 64;   // 512

__global__ __launch_bounds__(NTHR, 8) void atom_distances_kernel(
    const float* __restrict__ pos,    // [B, A, 3]
    const int*   __restrict__ nbr,    // [B, A, A]
    const int*   __restrict__ mask,   // [B, A]
    int*         __restrict__ ctr,    // [B] zeroed per launch, or nullptr
    float*       __restrict__ out,    // [B, A, A]
    int blocks_per_b) {
  __shared__ float    sx[A_DIM];             // 8 KB
  __shared__ f2       syz[A_DIM];            // 16 KB
  __shared__ unsigned smaskbits[A_DIM / 32]; // 256 B

  const int b = blockIdx.x / blocks_per_b;
  const int s = blockIdx.x % blocks_per_b;

  const float* posb  = pos  + (size_t)b * A_DIM * 3;
  const int*   maskb = mask + (size_t)b * A_DIM;

  for (int t = threadIdx.x; t < A_DIM; t += NTHR) {
    sx[t] = posb[3 * t + 0];
    f2 yz; yz.x = posb[3 * t + 1]; yz.y = posb[3 * t + 2];
    syz[t] = yz;
  }
  for (int r = 0; r < A_DIM / NTHR; ++r) {   // 4 rounds
    const int t = r * NTHR + threadIdx.x;
    const unsigned long long bal = __ballot(maskb[t] != 0);
    if ((threadIdx.x & 63) == 0) {
      const int wbase = t >> 5;
      smaskbits[wbase]     = (unsigned)bal;
      smaskbits[wbase + 1] = (unsigned)(bal >> 32);
    }
  }
  __syncthreads();

  const int lane = threadIdx.x & 63;
  const int w    = threadIdx.x >> 6;

  int* ctrb = ctr + b;

  // lane-0 ticket claim, broadcast to the wave
  #define GRAB() ({ int v_ = 0; if (lane == 0) v_ = atomicAdd(ctrb, 1); __shfl(v_, 0); })

  int row = ctr ? GRAB() : (s * WPB + w);

  while (row < A_DIM) {
    const int next = ctr ? GRAB() : A_DIM;   // prefetch next ticket

    const int i = row;
    float* orow = out + ((size_t)b * A_DIM + i) * A_DIM;
    const unsigned mi = (smaskbits[i >> 5] >> (i & 31)) & 1u;

    if (mi == 0) {
      const f4 z = {0.f, 0.f, 0.f, 0.f};
      #pragma unroll
      for (int c = 0; c < 8; ++c)
        __builtin_nontemporal_store(z, reinterpret_cast<f4*>(orow + (c * 64 + lane) * 4));
    } else {
      const float pix  = sx[i];
      const f2    piyz = syz[i];
      const int*  nrow = nbr + ((size_t)b * A_DIM + i) * A_DIM;

#define LDN(c) (*reinterpret_cast<const int4*>(nrow + ((c) * 64 + lane) * 4))

#define ELEM(nt_, e_, dst_) { \
    const int t_ = (nt_) & (A_DIM - 1); \
    const float xx_ = sx[t_]; \
    const f2 yz_ = syz[t_]; \
    const float dx_ = xx_ - pix; \
    const float dy_ = yz_.x - piyz.x; \
    const float dz_ = yz_.y - piyz.y; \
    const float d2_ = dx_ * dx_ + dy_ * dy_ + dz_ * dz_; \
    const float inv_ = d2_ > 0.0f ? __builtin_amdgcn_rsqf(d2_) : 1e8f; \
    dst_ = ((((wbits >> (bit + e_)) & 1u) != 0u) & (i != j0 + e_)) ? inv_ : 0.0f; }

#define PROC(c, n) { \
    const int j0 = ((c) * 64 + lane) * 4; \
    const unsigned wbits = smaskbits[(c) * 8 + (lane >> 3)]; \
    const int bit = (lane & 7) * 4; \
    f4 r; \
    ELEM(n.x, 0, r.x); \
    ELEM(n.y, 1, r.y); \
    ELEM(n.z, 2, r.z); \
    ELEM(n.w, 3, r.w); \
    __builtin_nontemporal_store(r, reinterpret_cast<f4*>(orow + j0)); }

      // depth-4 rotating neighbor prefetch
      int4 n0 = LDN(0), n1 = LDN(1), n2 = LDN(2), n3 = LDN(3);
      PROC(0, n0); n0 = LDN(4);
      PROC(1, n1); n1 = LDN(5);
      PROC(2, n2); n2 = LDN(6);
      PROC(3, n3); n3 = LDN(7);
      PROC(4, n0);
      PROC(5, n1);
      PROC(6, n2);
      PROC(7, n3);

#undef PROC
#undef ELEM
#undef LDN
    }

    row = next;
  }
  #undef GRAB
}

extern "C" void kernel_launch(void* const* d_in, const int* in_sizes, int n_in,
                              void* d_out, int out_size, void* d_ws, size_t ws_size,
                              hipStream_t stream) {
  const float* pos  = (const float*)d_in[0];  // [4,2048,3] f32
  const int*   nbr  = (const int*)d_in[1];    // [4,2048,2048] int32
  const int*   mask = (const int*)d_in[2];    // [4,2048] int32 (bool)
  float*       out  = (float*)d_out;          // [4,2048,2048] f32

  const int B = in_sizes[2] / A_DIM;          // 4

  int* ctr = nullptr;
  if (ws_size >= (size_t)B * sizeof(int)) {
    ctr = (int*)d_ws;
    hipMemsetAsync(ctr, 0, (size_t)B * sizeof(int), stream);  // tiny graph node
  }

  const int blocks_per_b = A_DIM / WPB;       // 256
  atom_distances_kernel<<<B * blocks_per_b, NTHR, 0, stream>>>(
      pos, nbr, mask, ctr, out, blocks_per_b);
}

// Round 6
// 22.351 us; speedup vs baseline: 9.3361x; 9.3361x over previous
//
#include <hip/hip_runtime.h>

// AtomDistances: out[b,i,j] = mask[b,i]&&mask[b,j]&&(i!=j)
//                  ? 1/(safe_norm(pos[b,nbr[b,i,j]] - pos[b,i]) + 1e-8) : 0
// B=4, A=2048.
//
// R6 = R3 skeleton (22.5us best) + two isolated LDS-pipe cuts:
//  (1) masked columns gather from address 0 (same-address broadcast = free)
//      instead of a random address -> ~halves bank-conflict serialization.
//  (2) positions packed x(b32)+yz(b64): 8 gather instrs/chunk vs 12.
// No atomics (R5 lesson: same-cacheline global atomics serialize @13ns),
// no prepass kernel (R4 lesson: serial graph node costs ~5us).

typedef float f4 __attribute__((ext_vector_type(4)));
typedef float f2 __attribute__((ext_vector_type(2)));

constexpr int A_DIM = 2048;
constexpr int WPB   = 8;          // rows (waves) per block
constexpr int NTHR  = WPB * 64;   // 512

__global__ __launch_bounds__(NTHR, 8) void atom_distances_kernel(
    const float* __restrict__ pos,    // [B, A, 3]
    const int*   __restrict__ nbr,    // [B, A, A]
    const int*   __restrict__ mask,   // [B, A]
    float*       __restrict__ out) {  // [B, A, A]
  __shared__ float    sx[A_DIM];             // 8 KB
  __shared__ f2       syz[A_DIM];            // 16 KB
  __shared__ unsigned smaskbits[A_DIM / 32]; // 256 B

  const int blocks_per_b = A_DIM / WPB;      // 256
  const int b  = blockIdx.x / blocks_per_b;
  const int i0 = (blockIdx.x % blocks_per_b) * WPB;

  const float* posb  = pos  + (size_t)b * A_DIM * 3;
  const int*   maskb = mask + (size_t)b * A_DIM;

  for (int t = threadIdx.x; t < A_DIM; t += NTHR) {
    sx[t] = posb[3 * t + 0];
    f2 yz; yz.x = posb[3 * t + 1]; yz.y = posb[3 * t + 2];
    syz[t] = yz;
  }
  for (int r = 0; r < A_DIM / NTHR; ++r) {   // 4 rounds
    const int t = r * NTHR + threadIdx.x;
    const unsigned long long bal = __ballot(maskb[t] != 0);
    if ((threadIdx.x & 63) == 0) {
      const int wbase = t >> 5;
      smaskbits[wbase]     = (unsigned)bal;
      smaskbits[wbase + 1] = (unsigned)(bal >> 32);
    }
  }
  __syncthreads();

  const int w    = threadIdx.x >> 6;
  const int lane = threadIdx.x & 63;
  const int i    = i0 + w;

  float* orow = out + ((size_t)b * A_DIM + i) * A_DIM;
  const unsigned mi = (smaskbits[i >> 5] >> (i & 31)) & 1u;

  if (mi == 0) {  // whole row masked -> zeros, wave exits early
    const f4 z = {0.f, 0.f, 0.f, 0.f};
    #pragma unroll
    for (int c = 0; c < 8; ++c)
      __builtin_nontemporal_store(z, reinterpret_cast<f4*>(orow + (c * 64 + lane) * 4));
    return;
  }

  const float pix  = sx[i];
  const f2    piyz = syz[i];
  const int*  nrow = nbr + ((size_t)b * A_DIM + i) * A_DIM;

#define LDN(c) (*reinterpret_cast<const int4*>(nrow + ((c) * 64 + lane) * 4))

// masked lanes gather from address 0 (wave-wide same-address broadcast: free)
#define ELEM(nt_, e_, dst_) { \
    const bool on_ = ((((wbits >> (bit + e_)) & 1u) != 0u) & (i != j0 + e_)); \
    const int t_ = on_ ? ((nt_) & (A_DIM - 1)) : 0; \
    const float xx_ = sx[t_]; \
    const f2 yz_ = syz[t_]; \
    const float dx_ = xx_ - pix; \
    const float dy_ = yz_.x - piyz.x; \
    const float dz_ = yz_.y - piyz.y; \
    const float d2_ = dx_ * dx_ + dy_ * dy_ + dz_ * dz_; \
    const float inv_ = d2_ > 0.0f ? __builtin_amdgcn_rsqf(d2_) : 1e8f; \
    dst_ = on_ ? inv_ : 0.0f; }

#define PROC(c, n) { \
    const int j0 = ((c) * 64 + lane) * 4; \
    const unsigned wbits = smaskbits[(c) * 8 + (lane >> 3)]; \
    const int bit = (lane & 7) * 4; \
    f4 r; \
    ELEM(n.x, 0, r.x); \
    ELEM(n.y, 1, r.y); \
    ELEM(n.z, 2, r.z); \
    ELEM(n.w, 3, r.w); \
    __builtin_nontemporal_store(r, reinterpret_cast<f4*>(orow + j0)); }

  // depth-4 rotating neighbor prefetch: 4 int4 loads always in flight
  int4 n0 = LDN(0), n1 = LDN(1), n2 = LDN(2), n3 = LDN(3);
  PROC(0, n0); n0 = LDN(4);
  PROC(1, n1); n1 = LDN(5);
  PROC(2, n2); n2 = LDN(6);
  PROC(3, n3); n3 = LDN(7);
  PROC(4, n0);
  PROC(5, n1);
  PROC(6, n2);
  PROC(7, n3);

#undef PROC
#undef ELEM
#undef LDN
}

extern "C" void kernel_launch(void* const* d_in, const int* in_sizes, int n_in,
                              void* d_out, int out_size, void* d_ws, size_t ws_size,
                              hipStream_t stream) {
  const float* pos  = (const float*)d_in[0];  // [4,2048,3] f32
  const int*   nbr  = (const int*)d_in[1];    // [4,2048,2048] int32
  const int*   mask = (const int*)d_in[2];    // [4,2048] int32 (bool)
  float*       out  = (float*)d_out;          // [4,2048,2048] f32

  const int B = in_sizes[2] / A_DIM;          // 4
  const int grid = B * (A_DIM / WPB);         // 1024 blocks

  atom_distances_kernel<<<grid, NTHR, 0, stream>>>(pos, nbr, mask, out);
}